// Round 4
// baseline (3136.845 us; speedup 1.0000x reference)
//
#include <hip/hip_runtime.h>

#define S_LEN   64
#define N_BATCH 65536
#define R_DIM   128
#define EMB_DIM 64
#define OUT_DIM 5
#define BN      64   // batch rows per block
#define NW      8    // waves per block

typedef unsigned short u16;
typedef unsigned short u16x8 __attribute__((ext_vector_type(8)));
typedef __bf16 bf16x8 __attribute__((ext_vector_type(8)));
typedef float f32x4 __attribute__((ext_vector_type(4)));

__device__ __forceinline__ u16 f2bf(float f) {
  unsigned u = __builtin_bit_cast(unsigned, f);
  u += 0x7fffu + ((u >> 16) & 1u);          // RNE
  return (u16)(u >> 16);
}
// v_cvt_pk_bf16_f32: low16 = bf16(a), high16 = bf16(b), RNE. 1 VALU op for 2 converts.
__device__ __forceinline__ unsigned cvt_pk_bf16(float a, float b) {
  unsigned r;
  asm("v_cvt_pk_bf16_f32 %0, %1, %2" : "=v"(r) : "v"(a), "v"(b));
  return r;
}
__device__ __forceinline__ f32x4 MFMA(u16x8 a, u16x8 b, f32x4 c) {
  return __builtin_amdgcn_mfma_f32_16x16x32_bf16(
      __builtin_bit_cast(bf16x8, a), __builtin_bit_cast(bf16x8, b), c, 0, 0, 0);
}
__device__ __forceinline__ float sigm(float x) {
  return __builtin_amdgcn_rcpf(1.0f + __expf(-x));   // mul+exp+add+rcp
}
__device__ __forceinline__ float tanh_fast(float x) {
  return 1.0f - 2.0f * __builtin_amdgcn_rcpf(1.0f + __expf(2.0f * x));
}

__global__ __launch_bounds__(512, 2) void vlstm_kernel(
    const float* __restrict__ x,      // (S,N,2)
    const float* __restrict__ h0,     // (N,128)
    const float* __restrict__ c0,     // (N,128)
    const int*   __restrict__ pmask,  // (S,N)
    const float* __restrict__ Wemb,   // (64,2)
    const float* __restrict__ bemb,   // (64)
    const float* __restrict__ Wih,    // (512,64)
    const float* __restrict__ Whh,    // (512,128)
    const float* __restrict__ bih,    // (512)
    const float* __restrict__ bhh,    // (512)
    const float* __restrict__ Wout,   // (5,128)
    const float* __restrict__ bout,   // (5)
    float* __restrict__ out)          // (S,N,5) | h_final (N,128) | c_final (N,128)
{
  // Double-buffered bf16 h (row stride 256B) and e (128B), XOR-swizzled (byte ^= (row&7)<<4).
  __shared__ __align__(16) u16 h_sh[2][BN * 128];   // 2 x 16 KiB
  __shared__ __align__(16) u16 e_sh[2][BN * 64];    // 2 x 8 KiB
  __shared__ int   mring[4][BN];                    // 4-deep mask ring (C reads t, D reads t-1, A writes t+1)
  __shared__ float out_sh[2][BN * OUT_DIM];         // staged out rows, double-buffered
  __shared__ float wemb_sh[EMB_DIM * 2];
  __shared__ float bemb_sh[EMB_DIM];

  const int tid  = threadIdx.x;
  const int w    = tid >> 6;
  const int ln   = tid & 63;
  const int lo   = ln & 15;
  const int hi   = ln >> 4;
  const int base = blockIdx.x * BN;
  const int gcb  = w * 16 + lo;

  if (tid < EMB_DIM * 2) wemb_sh[tid] = Wemb[tid];
  if (tid < EMB_DIM)     bemb_sh[tid] = bemb[tid];

  // ---- weight fragments (bf16) resident in registers -----------------------
  u16x8 wih[4][2], whh[4][4], wout_f[4];
  float bias_g[4];
#pragma unroll
  for (int q = 0; q < 4; ++q) {
    const int gc = q * 128 + gcb;
    const float* wp = Wih + gc * 64 + hi * 8;
#pragma unroll
    for (int ks = 0; ks < 2; ++ks)
#pragma unroll
      for (int j = 0; j < 8; ++j) wih[q][ks][j] = f2bf(wp[ks * 32 + j]);
    const float* wq = Whh + gc * 128 + hi * 8;
#pragma unroll
    for (int ks = 0; ks < 4; ++ks)
#pragma unroll
      for (int j = 0; j < 8; ++j) whh[q][ks][j] = f2bf(wq[ks * 32 + j]);
    bias_g[q] = bih[gc] + bhh[gc];
  }
#pragma unroll
  for (int ks = 0; ks < 4; ++ks)
#pragma unroll
    for (int j = 0; j < 8; ++j)
      wout_f[ks][j] = (lo < OUT_DIM) ? f2bf(Wout[lo * 128 + ks * 32 + hi * 8 + j]) : (u16)0;
  const float bout_v = (lo < OUT_DIM) ? bout[lo] : 0.0f;

  // ---- stage h0 -> h_sh[0] (bf16, swizzled) --------------------------------
  {
    const int row = tid >> 3;
    const int cb  = (tid & 7) * 16;
    const float* hp = h0 + (size_t)(base + row) * 128 + cb;
#pragma unroll
    for (int half = 0; half < 2; ++half) {
      unsigned vv[4];
#pragma unroll
      for (int jj = 0; jj < 4; ++jj)
        vv[jj] = cvt_pk_bf16(hp[half * 8 + jj * 2], hp[half * 8 + jj * 2 + 1]);
      const int byte = row * 256 + ((((cb + half * 8) * 2)) ^ ((row & 7) << 4));
      *(uint4*)((char*)h_sh[0] + byte) = *(uint4*)vv;
    }
  }
  // ---- c0 -> cst regs (fp32); h0 -> hreg regs (fp32, own slice) ------------
  float cst[4][4], hreg[4][4];
#pragma unroll
  for (int rt = 0; rt < 4; ++rt)
#pragma unroll
    for (int r = 0; r < 4; ++r) {
      const size_t idx = (size_t)(base + rt * 16 + hi * 4 + r) * 128 + gcb;
      cst[rt][r]  = c0[idx];
      hreg[rt][r] = h0[idx];
    }

  // ---- phase A helper: embed + mask publish --------------------------------
  const int arow = tid & 63;
  const int akb  = tid >> 6;
  auto phaseA = [&](int eslot, int mslot, float2 xvv, int mkk) {
    unsigned ev32[4];
#pragma unroll
    for (int jj = 0; jj < 4; ++jj) {
      const int k0 = akb * 8 + jj * 2;
      float e0 = fmaf(xvv.y, wemb_sh[2 * k0 + 1], fmaf(xvv.x, wemb_sh[2 * k0], bemb_sh[k0]));
      float e1 = fmaf(xvv.y, wemb_sh[2 * k0 + 3], fmaf(xvv.x, wemb_sh[2 * k0 + 2], bemb_sh[k0 + 1]));
      ev32[jj] = cvt_pk_bf16(fmaxf(e0, 0.0f), fmaxf(e1, 0.0f));
    }
    const int byte = arow * 128 + ((akb * 16) ^ ((arow & 7) << 4));
    *(uint4*)((char*)e_sh[eslot] + byte) = *(uint4*)ev32;
    if (akb == 0) mring[mslot][arow] = mkk;
  };

  // ---- prologue: A(0) + prefetch(1) ---------------------------------------
  {
    const float2 xv0 = *(const float2*)(x + (size_t)(base + arow) * 2);
    const int    mk0 = pmask[base + arow];
    phaseA(0, 0, xv0, mk0);
  }
  float2 xv_h = *(const float2*)(x + ((size_t)N_BATCH + base + arow) * 2);
  int    mk_h = pmask[(size_t)N_BATCH + base + arow];
  __syncthreads();

  float* const out_seq = out;
  float* const out_h   = out + (size_t)S_LEN * N_BATCH * OUT_DIM;
  float* const out_c   = out_h + (size_t)N_BATCH * R_DIM;

  // ======================= main loop: ONE barrier per step ==================
  for (int t = 0; t < S_LEN; ++t) {
    const int cur = t & 1, nxt = cur ^ 1;
    const char* hcur = (const char*)h_sh[cur];
    const char* ecur = (const char*)e_sh[cur];
    char*       hnxt = (char*)h_sh[nxt];

    // ---- B: gate MFMAs from h_sh[cur], e_sh[cur] --------------------------
    f32x4 acc[4][4];
#pragma unroll
    for (int rt = 0; rt < 4; ++rt)
#pragma unroll
      for (int q = 0; q < 4; ++q) {
        f32x4 b = {bias_g[q], bias_g[q], bias_g[q], bias_g[q]};
        acc[rt][q] = b;
      }
#pragma unroll
    for (int rt = 0; rt < 4; ++rt) {
      const int row = rt * 16 + lo;
      const int swz = (row & 7) << 4;
      const char* hrow = hcur + row * 256;
      const char* erow = ecur + row * 128;
      u16x8 ae0 = *(const u16x8*)(erow + ((hi * 16      ) ^ swz));
      u16x8 ae1 = *(const u16x8*)(erow + ((hi * 16 +  64) ^ swz));
      u16x8 ah0 = *(const u16x8*)(hrow + ((hi * 16      ) ^ swz));
      u16x8 ah1 = *(const u16x8*)(hrow + ((hi * 16 +  64) ^ swz));
      u16x8 ah2 = *(const u16x8*)(hrow + ((hi * 16 + 128) ^ swz));
      u16x8 ah3 = *(const u16x8*)(hrow + ((hi * 16 + 192) ^ swz));
#pragma unroll
      for (int q = 0; q < 4; ++q) {
        f32x4 a = acc[rt][q];
        a = MFMA(ae0, wih[q][0], a);
        a = MFMA(ae1, wih[q][1], a);
        a = MFMA(ah0, whh[q][0], a);
        a = MFMA(ah1, whh[q][1], a);
        a = MFMA(ah2, whh[q][2], a);
        a = MFMA(ah3, whh[q][3], a);
        acc[rt][q] = a;
      }
    }

    // ---- D(t-1): out-projection, reads h_sh[cur] (= h_{t-1}, read-read w/ B)
    if (t > 0 && w < 4) {
      const int rt  = w;
      const int row = rt * 16 + lo;
      const int swz = (row & 7) << 4;
      const char* hrow = hcur + row * 256;
      u16x8 a0 = *(const u16x8*)(hrow + ((hi * 16      ) ^ swz));
      u16x8 a1 = *(const u16x8*)(hrow + ((hi * 16 +  64) ^ swz));
      u16x8 a2 = *(const u16x8*)(hrow + ((hi * 16 + 128) ^ swz));
      u16x8 a3 = *(const u16x8*)(hrow + ((hi * 16 + 192) ^ swz));
      f32x4 oa = {bout_v, bout_v, bout_v, bout_v};
      oa = MFMA(a0, wout_f[0], oa);
      oa = MFMA(a1, wout_f[1], oa);
      oa = MFMA(a2, wout_f[2], oa);
      oa = MFMA(a3, wout_f[3], oa);
      if (lo < OUT_DIM) {
#pragma unroll
        for (int r = 0; r < 4; ++r) {
          const int orow = rt * 16 + hi * 4 + r;
          out_sh[(t - 1) & 1][orow * OUT_DIM + lo] =
              mring[(t - 1) & 3][orow] ? oa[r] : 0.0f;
        }
      }
    }

    // ---- store(t-2): fully coalesced 1280B block --------------------------
    if (t >= 2 && tid < BN * OUT_DIM)
      out_seq[((size_t)(t - 2) * N_BATCH + base) * OUT_DIM + tid] = out_sh[t & 1][tid];

    // ---- C: nonlinearities + masked update; write h_sh[nxt] ALWAYS --------
#pragma unroll
    for (int rt = 0; rt < 4; ++rt) {
#pragma unroll
      for (int r = 0; r < 4; ++r) {
        const int row = rt * 16 + hi * 4 + r;
        const bool m = mring[t & 3][row] != 0;
        const float iv = sigm(acc[rt][0][r]);
        const float fv = sigm(acc[rt][1][r]);
        const float gv = tanh_fast(acc[rt][2][r]);
        const float ov = sigm(acc[rt][3][r]);
        const float cn = fmaf(fv, cst[rt][r], iv * gv);
        const float hn = ov * tanh_fast(cn);
        cst[rt][r]  = m ? cn : cst[rt][r];
        const float hk = m ? hn : hreg[rt][r];
        hreg[rt][r] = hk;
        const int byte = row * 256 + ((gcb * 2) ^ ((row & 7) << 4));
        *(u16*)(hnxt + byte) = (u16)cvt_pk_bf16(hk, hk);
      }
    }

    // ---- A(t+1): embed next step into e_sh[nxt]; prefetch t+2 -------------
    if (t < S_LEN - 1) {
      phaseA(nxt, (t + 1) & 3, xv_h, mk_h);
      if (t < S_LEN - 2) {
        xv_h = *(const float2*)(x + ((size_t)(t + 2) * N_BATCH + base + arow) * 2);
        mk_h = pmask[(size_t)(t + 2) * N_BATCH + base + arow];
      }
    }

    __syncthreads();   // the ONE barrier per step
  }

  // ======================= epilogue ========================================
  // D(63): h_new(63) lives in h_sh[nxt(63)] = h_sh[0]
  if (w < 4) {
    const int rt  = w;
    const int row = rt * 16 + lo;
    const int swz = (row & 7) << 4;
    const char* hrow = (const char*)h_sh[0] + row * 256;
    u16x8 a0 = *(const u16x8*)(hrow + ((hi * 16      ) ^ swz));
    u16x8 a1 = *(const u16x8*)(hrow + ((hi * 16 +  64) ^ swz));
    u16x8 a2 = *(const u16x8*)(hrow + ((hi * 16 + 128) ^ swz));
    u16x8 a3 = *(const u16x8*)(hrow + ((hi * 16 + 192) ^ swz));
    f32x4 oa = {bout_v, bout_v, bout_v, bout_v};
    oa = MFMA(a0, wout_f[0], oa);
    oa = MFMA(a1, wout_f[1], oa);
    oa = MFMA(a2, wout_f[2], oa);
    oa = MFMA(a3, wout_f[3], oa);
    if (lo < OUT_DIM) {
#pragma unroll
      for (int r = 0; r < 4; ++r) {
        const int orow = rt * 16 + hi * 4 + r;
        out_sh[1][orow * OUT_DIM + lo] = mring[3][orow] ? oa[r] : 0.0f;
      }
    }
  }
  if (tid < BN * OUT_DIM)   // store(62): D(62) wrote out_sh[0] in window t=63
    out_seq[((size_t)62 * N_BATCH + base) * OUT_DIM + tid] = out_sh[0][tid];
  __syncthreads();
  if (tid < BN * OUT_DIM)   // store(63)
    out_seq[((size_t)63 * N_BATCH + base) * OUT_DIM + tid] = out_sh[1][tid];

  // finals from fp32 registers (exact propagation for masked rows)
#pragma unroll
  for (int rt = 0; rt < 4; ++rt)
#pragma unroll
    for (int r = 0; r < 4; ++r) {
      const size_t idx = (size_t)(base + rt * 16 + hi * 4 + r) * 128 + gcb;
      out_h[idx] = hreg[rt][r];
      out_c[idx] = cst[rt][r];
    }
}

extern "C" void kernel_launch(void* const* d_in, const int* in_sizes, int n_in,
                              void* d_out, int out_size, void* d_ws, size_t ws_size,
                              hipStream_t stream) {
  (void)in_sizes; (void)n_in; (void)out_size; (void)d_ws; (void)ws_size;
  const int grid = N_BATCH / BN;   // 1024 blocks
  vlstm_kernel<<<grid, 512, 0, stream>>>(
      (const float*)d_in[0], (const float*)d_in[1], (const float*)d_in[2],
      (const int*)d_in[3],
      (const float*)d_in[4], (const float*)d_in[5],
      (const float*)d_in[6], (const float*)d_in[7],
      (const float*)d_in[8], (const float*)d_in[9],
      (const float*)d_in[10], (const float*)d_in[11],
      (float*)d_out);
}